// Round 2
// baseline (125.329 us; speedup 1.0000x reference)
//
#include <hip/hip_runtime.h>

// Problem: B=64, S1=1024, S2=1024, DV=256.
// Key insight: softmax over j of (sx[i] + sk[j] + b0) == softmax(sk)[j]
// (shift invariance), so attn is independent of i; output row is identical
// for all i within a batch. x, W[0:3], b are mathematically irrelevant.

#define NB 64
#define S1V 1024
#define S2V 1024
#define DVV 256
#define NCHUNK 8          // j-chunks for PV partial sums
#define JPC (S2V / NCHUNK) // 128 j per chunk

// ws layout (floats):
//   p       : NB*S2V            @ byte offset 0        (256 KB)
//   partial : NB*NCHUNK*DVV     @ byte offset 262144   (512 KB)
//   row     : NB*DVV            @ byte offset 786432   (64 KB)

__global__ __launch_bounds__(256) void k_softmax(const float* __restrict__ key,
                                                 const float* __restrict__ W,
                                                 float* __restrict__ p) {
    const int b = blockIdx.x;
    const int t = threadIdx.x;
    const float wk0 = W[3], wk1 = W[4], wk2 = W[5];

    // thread t handles j = 4t..4t+3 ; 12 consecutive floats = 3 float4
    const float4* k4 = (const float4*)(key + (size_t)b * S2V * 3);
    float4 a = k4[3 * t + 0];
    float4 c = k4[3 * t + 1];
    float4 d = k4[3 * t + 2];
    float sk0 = a.x * wk0 + a.y * wk1 + a.z * wk2;
    float sk1 = a.w * wk0 + c.x * wk1 + c.y * wk2;
    float sk2 = c.z * wk0 + c.w * wk1 + d.x * wk2;
    float sk3 = d.y * wk0 + d.z * wk1 + d.w * wk2;

    // block max over 1024 sk values
    float m = fmaxf(fmaxf(sk0, sk1), fmaxf(sk2, sk3));
    for (int off = 32; off; off >>= 1) m = fmaxf(m, __shfl_xor(m, off));
    __shared__ float redm[4];
    const int wave = t >> 6, lane = t & 63;
    if (lane == 0) redm[wave] = m;
    __syncthreads();
    m = fmaxf(fmaxf(redm[0], redm[1]), fmaxf(redm[2], redm[3]));

    float e0 = __expf(sk0 - m), e1 = __expf(sk1 - m);
    float e2 = __expf(sk2 - m), e3 = __expf(sk3 - m);
    float s = e0 + e1 + e2 + e3;
    for (int off = 32; off; off >>= 1) s += __shfl_xor(s, off);
    __shared__ float reds[4];
    if (lane == 0) reds[wave] = s;
    __syncthreads();
    s = reds[0] + reds[1] + reds[2] + reds[3];

    const float inv = 1.0f / s;
    float4 out4 = make_float4(e0 * inv, e1 * inv, e2 * inv, e3 * inv);
    ((float4*)(p + (size_t)b * S2V))[t] = out4;
}

__global__ __launch_bounds__(256) void k_pv(const float* __restrict__ value,
                                            const float* __restrict__ p,
                                            float* __restrict__ partial) {
    const int b = blockIdx.x >> 3;
    const int chunk = blockIdx.x & (NCHUNK - 1);
    const int t = threadIdx.x;
    const int wave = t >> 6, lane = t & 63;

    __shared__ float p_lds[JPC];
    if (t < JPC) p_lds[t] = p[(size_t)b * S2V + chunk * JPC + t];
    __syncthreads();

    // wave w covers j = chunk*128 + w*32 + i, i=0..31 ; lane owns 4 d's (float4)
    const float4* v4 = (const float4*)(value + (size_t)b * S2V * DVV);
    float4 acc = make_float4(0.f, 0.f, 0.f, 0.f);
    const int jbase = chunk * JPC + wave * 32;
    #pragma unroll 8
    for (int i = 0; i < 32; ++i) {
        const int j = jbase + i;
        const float pj = p_lds[wave * 32 + i];
        float4 v = v4[(size_t)j * 64 + lane];
        acc.x += pj * v.x;
        acc.y += pj * v.y;
        acc.z += pj * v.z;
        acc.w += pj * v.w;
    }

    __shared__ float4 accl[256];
    accl[t] = acc;
    __syncthreads();
    if (wave == 0) {
        float4 r0 = accl[lane];
        float4 r1 = accl[64 + lane];
        float4 r2 = accl[128 + lane];
        float4 r3 = accl[192 + lane];
        r0.x += r1.x + r2.x + r3.x;
        r0.y += r1.y + r2.y + r3.y;
        r0.z += r1.z + r2.z + r3.z;
        r0.w += r1.w + r2.w + r3.w;
        ((float4*)(partial + ((size_t)b * NCHUNK + chunk) * DVV))[lane] = r0;
    }
}

__global__ __launch_bounds__(256) void k_reduce(const float* __restrict__ partial,
                                                float* __restrict__ row) {
    const int b = blockIdx.x;
    const int t = threadIdx.x;
    float acc = 0.f;
    #pragma unroll
    for (int c = 0; c < NCHUNK; ++c)
        acc += partial[((size_t)b * NCHUNK + c) * DVV + t];
    row[(size_t)b * DVV + t] = acc;
}

__global__ __launch_bounds__(256) void k_bcast(const float* __restrict__ row,
                                               float* __restrict__ out) {
    // 128 blocks per batch, each writes 8 rows of 256 floats (64 float4)
    const int b = blockIdx.x >> 7;
    const int rt = blockIdx.x & 127;
    const int t = threadIdx.x;
    const int d4 = t & 63;
    const int rsub = t >> 6; // 0..3

    float4 r = ((const float4*)(row + (size_t)b * DVV))[d4];
    float4* out4 = (float4*)(out + ((size_t)b * S1V + (size_t)rt * 8) * DVV);
    out4[(size_t)rsub * 64 + d4] = r;
    out4[(size_t)(rsub + 4) * 64 + d4] = r;
}

extern "C" void kernel_launch(void* const* d_in, const int* in_sizes, int n_in,
                              void* d_out, int out_size, void* d_ws, size_t ws_size,
                              hipStream_t stream) {
    // inputs: 0=x (unused), 1=key, 2=value, 3=W, 4=b (unused)
    const float* key   = (const float*)d_in[1];
    const float* value = (const float*)d_in[2];
    const float* W     = (const float*)d_in[3];
    float* out = (float*)d_out;

    float* p       = (float*)d_ws;                              // 256 KB
    float* partial = (float*)((char*)d_ws + 262144);            // 512 KB
    float* row     = (float*)((char*)d_ws + 786432);            // 64 KB

    k_softmax<<<NB, 256, 0, stream>>>(key, W, p);
    k_pv<<<NB * NCHUNK, 256, 0, stream>>>(value, p, partial);
    k_reduce<<<NB, 256, 0, stream>>>(partial, row);
    k_bcast<<<NB * 128, 256, 0, stream>>>(row, out);
}

// Round 14
// 119.935 us; speedup vs baseline: 1.0450x; 1.0450x over previous
//
#include <hip/hip_runtime.h>

// B=64, S1=1024, S2=1024, DV=256.
// softmax(sx[i]+sk[j]+b0) over j == softmax(sk)[j]  (shift invariance)
// => attn row identical for all i; out[b,i,:] = sum_j softmax(sk)[j]*value[b,j,:].
// x, W[0:3], b never affect the output.
//
// Two kernels:
//  A (k_pv): 1024 blocks = 64 batches x 16 chunks. Each block recomputes the
//    batch softmax stats (12 KB key read, L2-cached across the 16 sibling
//    blocks), then reduces its 64-row value chunk. Writes 1 MB of partials.
//  B (k_out): 8192 blocks. Sums the 16 partials per (b,d) (L2-resident) and
//    broadcast-writes the 64 MB output with non-temporal float4 stores.

#define NB 64
#define S1V 1024
#define S2V 1024
#define DVV 256
#define NCHUNK 16
#define JPC (S2V / NCHUNK)   // 64 j per chunk

typedef float nf4 __attribute__((ext_vector_type(4)));  // nontemporal-capable float4

// ws layout: partial = NB*NCHUNK*DVV floats = 1 MB @ offset 0

__global__ __launch_bounds__(256) void k_pv(const float* __restrict__ key,
                                            const float* __restrict__ value,
                                            const float* __restrict__ W,
                                            float* __restrict__ partial) {
    const int b     = blockIdx.x >> 4;          // / NCHUNK
    const int chunk = blockIdx.x & (NCHUNK - 1);
    const int t     = threadIdx.x;
    const int wave  = t >> 6, lane = t & 63;

    const float wk0 = W[3], wk1 = W[4], wk2 = W[5];

    // ---- softmax stats over all 1024 j (thread t owns j = 4t..4t+3) ----
    const float4* k4 = (const float4*)(key + (size_t)b * S2V * 3);
    float4 a = k4[3 * t + 0];
    float4 c = k4[3 * t + 1];
    float4 d = k4[3 * t + 2];
    float sk0 = fmaf(a.x, wk0, fmaf(a.y, wk1, a.z * wk2));
    float sk1 = fmaf(a.w, wk0, fmaf(c.x, wk1, c.y * wk2));
    float sk2 = fmaf(c.z, wk0, fmaf(c.w, wk1, d.x * wk2));
    float sk3 = fmaf(d.y, wk0, fmaf(d.z, wk1, d.w * wk2));

    __shared__ float redm[4], reds[4];

    float m = fmaxf(fmaxf(sk0, sk1), fmaxf(sk2, sk3));
    #pragma unroll
    for (int off = 32; off; off >>= 1) m = fmaxf(m, __shfl_xor(m, off));
    if (lane == 0) redm[wave] = m;
    __syncthreads();
    m = fmaxf(fmaxf(redm[0], redm[1]), fmaxf(redm[2], redm[3]));

    float e0 = __expf(sk0 - m), e1 = __expf(sk1 - m);
    float e2 = __expf(sk2 - m), e3 = __expf(sk3 - m);
    float s = e0 + e1 + e2 + e3;
    #pragma unroll
    for (int off = 32; off; off >>= 1) s += __shfl_xor(s, off);
    if (lane == 0) reds[wave] = s;
    __syncthreads();
    s = reds[0] + reds[1] + reds[2] + reds[3];
    const float inv = 1.0f / s;

    // ---- stash this chunk's 64 p values ----
    __shared__ float p_lds[JPC];
    const int tlo = chunk * (JPC / 4);          // 16 threads own this chunk
    if (t >= tlo && t < tlo + JPC / 4) {
        const int q = (t - tlo) * 4;
        p_lds[q + 0] = e0 * inv;
        p_lds[q + 1] = e1 * inv;
        p_lds[q + 2] = e2 * inv;
        p_lds[q + 3] = e3 * inv;
    }
    __syncthreads();

    // ---- PV partial: wave w owns j = chunk*64 + w*16 + i ----
    const float4* v4 = (const float4*)(value + (size_t)b * S2V * DVV);
    const int jbase = chunk * JPC + wave * (JPC / 4);
    float4 acc = make_float4(0.f, 0.f, 0.f, 0.f);
    #pragma unroll
    for (int i = 0; i < JPC / 4; ++i) {
        const float pj = p_lds[wave * (JPC / 4) + i];
        float4 v = v4[(size_t)(jbase + i) * 64 + lane];
        acc.x = fmaf(pj, v.x, acc.x);
        acc.y = fmaf(pj, v.y, acc.y);
        acc.z = fmaf(pj, v.z, acc.z);
        acc.w = fmaf(pj, v.w, acc.w);
    }

    __shared__ float4 accl[256];
    accl[t] = acc;
    __syncthreads();
    if (wave == 0) {
        float4 r0 = accl[lane];
        float4 r1 = accl[64 + lane];
        float4 r2 = accl[128 + lane];
        float4 r3 = accl[192 + lane];
        r0.x += r1.x + r2.x + r3.x;
        r0.y += r1.y + r2.y + r3.y;
        r0.z += r1.z + r2.z + r3.z;
        r0.w += r1.w + r2.w + r3.w;
        ((float4*)(partial + ((size_t)b * NCHUNK + chunk) * DVV))[lane] = r0;
    }
}

__global__ __launch_bounds__(256) void k_out(const float* __restrict__ partial,
                                             float* __restrict__ out) {
    // 128 blocks per batch; each block writes 8 rows of 256 floats.
    const int b    = blockIdx.x >> 7;
    const int rt   = blockIdx.x & 127;
    const int t    = threadIdx.x;
    const int d4   = t & 63;
    const int rsub = t >> 6;                    // 0..3

    // wave `rsub` sums chunks [rsub*4, rsub*4+4) for its d4
    const float4* pp = (const float4*)(partial + (size_t)b * NCHUNK * DVV);
    float4 acc = make_float4(0.f, 0.f, 0.f, 0.f);
    #pragma unroll
    for (int c = rsub * 4; c < rsub * 4 + 4; ++c) {
        float4 v = pp[c * 64 + d4];
        acc.x += v.x; acc.y += v.y; acc.z += v.z; acc.w += v.w;
    }
    __shared__ float4 accl[256];
    accl[t] = acc;
    __syncthreads();
    float4 r = accl[d4];
    float4 r1 = accl[64 + d4];
    float4 r2 = accl[128 + d4];
    float4 r3 = accl[192 + d4];
    r.x += r1.x + r2.x + r3.x;
    r.y += r1.y + r2.y + r3.y;
    r.z += r1.z + r2.z + r3.z;
    r.w += r1.w + r2.w + r3.w;

    nf4 rv = { r.x, r.y, r.z, r.w };
    nf4* out4 = (nf4*)(out + ((size_t)b * S1V + (size_t)rt * 8) * DVV);
    __builtin_nontemporal_store(rv, &out4[(size_t)rsub * 64 + d4]);
    __builtin_nontemporal_store(rv, &out4[(size_t)(rsub + 4) * 64 + d4]);
}

extern "C" void kernel_launch(void* const* d_in, const int* in_sizes, int n_in,
                              void* d_out, int out_size, void* d_ws, size_t ws_size,
                              hipStream_t stream) {
    // inputs: 0=x (unused), 1=key, 2=value, 3=W, 4=b (unused)
    const float* key   = (const float*)d_in[1];
    const float* value = (const float*)d_in[2];
    const float* W     = (const float*)d_in[3];
    float* out = (float*)d_out;

    float* partial = (float*)d_ws;   // 1 MB

    k_pv<<<NB * NCHUNK, 256, 0, stream>>>(key, value, W, partial);
    k_out<<<NB * 128, 256, 0, stream>>>(partial, out);
}